// Round 8
// baseline (107.924 us; speedup 1.0000x reference)
//
#include <hip/hip_runtime.h>
#include <math.h>

#define POOL 7
#define FH 50
#define FW 50
#define FC 1024
#define FC4 (FC / 4)        // 256 vf4 per spatial cell
#define CHUNKS 4            // channel chunks; 64 vf4 (256 ch) per chunk
#define F4C 64              // vf4 per cell per chunk (one wave-wide load)
#define RS (FW * FC4)       // row stride in vf4
#define JGROUPS 4
#define UNITS_PER_ROI (POOL * JGROUPS)   // 28
#define GRID 1024           // persistent: 4 blocks/CU

typedef float vf4 __attribute__((ext_vector_type(4)));

static __device__ __forceinline__ vf4 vmax4(vf4 a, vf4 b) {
    vf4 r;
    r.x = fmaxf(a.x, b.x);
    r.y = fmaxf(a.y, b.y);
    r.z = fmaxf(a.z, b.z);
    r.w = fmaxf(a.w, b.w);
    return r;
}

// Max over one bin of hr x wd cells starting at p0 (already offset to this
// wave's chunk/lane vf4), row stride RS, col stride FC4.
//
// WHY INLINE ASM: R6's profile showed VGPR_Count=44 — the compiler rewrote
// R5's "12 independent loads" into load->wait->consume pairs to minimize
// registers, so measured in-flight was ~0.5 loads/wave (433MB / 44.8us =
// 15.7 B/cy/CU = ~4 KB outstanding per CU at ~250cy L2 latency). Every
// C-level restructuring (R0-R7) compiled to the same ~2-deep pipeline,
// which is why all seven rounds landed at 44-46 us. This batch — EIGHT
// global_load_dwordx4 plus ONE trailing s_waitcnt vmcnt(0) inside a single
// asm block with eight distinct early-clobber 128-bit outputs — cannot be
// serialized by the register allocator: 8 KB per wave guaranteed in
// flight. Loads+wait live in the same block, so outputs are defined at
// block end (no hoisting hazard; rule-18 pattern avoided by construction).
//
// Cell addresses advance by incremental counters (no runtime div); the
// last batch re-issues the final cell for padding lanes — duplicate loads
// are idempotent under max and L1-resident.
static __device__ __forceinline__ vf4 pool_bin8(const vf4* p0, int hr, int wd)
{
    vf4 acc = {-INFINITY, -INFINITY, -INFINITY, -INFINITY};
    const int cells = hr * wd;
    const int nb = (cells + 7) >> 3;
    const vf4* p = p0;
    int co = 0;
    for (int bk = 0; bk < nb; ++bk) {
        const vf4* ap[8];   // only constant-indexed in the unrolled loop
#pragma unroll
        for (int k = 0; k < 8; ++k) {
            ap[k] = p;
            const bool adv  = (bk * 8 + k) < (cells - 1);
            const int  con  = co + 1;
            const bool wrap = (con == wd);
            const vf4* pn   = wrap ? (p + (RS - (wd - 1) * FC4)) : (p + FC4);
            p  = adv ? pn : p;
            co = adv ? (wrap ? 0 : con) : co;
        }
        vf4 d0, d1, d2, d3, d4, d5, d6, d7;
        asm volatile(
            "global_load_dwordx4 %0, %8, off\n\t"
            "global_load_dwordx4 %1, %9, off\n\t"
            "global_load_dwordx4 %2, %10, off\n\t"
            "global_load_dwordx4 %3, %11, off\n\t"
            "global_load_dwordx4 %4, %12, off\n\t"
            "global_load_dwordx4 %5, %13, off\n\t"
            "global_load_dwordx4 %6, %14, off\n\t"
            "global_load_dwordx4 %7, %15, off\n\t"
            "s_waitcnt vmcnt(0)"
            : "=&v"(d0), "=&v"(d1), "=&v"(d2), "=&v"(d3),
              "=&v"(d4), "=&v"(d5), "=&v"(d6), "=&v"(d7)
            : "v"(ap[0]), "v"(ap[1]), "v"(ap[2]), "v"(ap[3]),
              "v"(ap[4]), "v"(ap[5]), "v"(ap[6]), "v"(ap[7])
            : "memory");
        acc = vmax4(acc, vmax4(vmax4(d0, d1), vmax4(d2, d3)));
        acc = vmax4(acc, vmax4(vmax4(d4, d5), vmax4(d6, d7)));
    }
    return acc;
}

// Persistent-wave RoI max-pool, asm-batched loads. Grid/decomposition =
// R6 verbatim: 1024 blocks (4/CU), wave = (roi, row-bin, col-bin-pair,
// chunk) grid-strided; chunk = b&3 pinned per XCD (b%8 round-robin) keeps
// each 2.56 MB fm slice L2-resident (FETCH 8.4 MB confirmed in R6).
// Only the load body changed (pool_bin8). Tables dropped (R7: null).
__global__ __launch_bounds__(256) void roipool_kernel(
    const float* __restrict__ fm,     // [FH, FW, FC]
    const float* __restrict__ rois,   // [N, 4] (y1, x1, y2, x2) normalized
    float* __restrict__ out,          // [N, 7, 7, FC]
    int nunits)
{
    const int b     = blockIdx.x;
    const int chunk = b & (CHUNKS - 1);       // pinned per XCD
    const int wave  = threadIdx.x >> 6;
    const int lane  = threadIdx.x & 63;
    const int wv    = (b >> 2) * 4 + wave;

    const int f4 = chunk * F4C + lane;        // [0, 256)
    const vf4* base = reinterpret_cast<const vf4*>(fm) + f4;

    for (int u = wv; u < nunits; u += GRID) {
        const int n   = u / UNITS_PER_ROI;
        const int rem = u - n * UNITS_PER_ROI;
        const int i   = rem >> 2;
        const int jg  = rem & 3;
        const int j0  = jg * 2;
        const int jcnt = (jg < JGROUPS - 1) ? 2 : 1;

        // ROI corners: truncating float->int cast, matching jnp astype(int32)
        const float4 roi = reinterpret_cast<const float4*>(rois)[n];
        const int h0 = (int)((float)FH * roi.x);
        const int w0 = (int)((float)FW * roi.y);
        const int h1 = (int)((float)FH * roi.z);
        const int w1 = (int)((float)FW * roi.w);
        const int rh = h1 - h0;
        const int rw = w1 - w0;
        const int hstep = rh / POOL;
        const int wstep = rw / POOL;

        vf4* o = reinterpret_cast<vf4*>(out)
               + (size_t)(n * 49 + i * 7 + j0) * FC4 + f4;

        if (hstep >= 1 && wstep >= 1 && wstep <= 3) {
            // ---- fast path: bins exactly partition (verified R5-R7) ----
            const int row0 = h0 + i * hstep;
            const int hr   = (i < POOL - 1) ? hstep : (rh - 6 * hstep); // >=1
            // bin 0 of the pair (or the lone last bin for jg==3)
            {
                const int wd   = (jg < 3) ? wstep : (rw - 6 * wstep);
                const int colb = w0 + j0 * wstep;
                const vf4* p0  = base + (size_t)row0 * RS + (size_t)colb * FC4;
                vf4 a0 = pool_bin8(p0, hr, wd);
                __builtin_nontemporal_store(a0, o);
            }
            if (jcnt == 2) {
                const int colb = w0 + (j0 + 1) * wstep;
                const vf4* p0  = base + (size_t)row0 * RS + (size_t)colb * FC4;
                vf4 a1 = pool_bin8(p0, hr, wstep);
                __builtin_nontemporal_store(a1, o + (size_t)FC4);
            }
        } else {
            // ---- generic fallback (degenerate ROIs): round-2 code ----
            int sh = i * hstep;
            int eh = (i < POOL - 1) ? (i + 1) * hstep : rh;
            if (sh == eh) { if (eh < rh) eh += 1; else sh -= 1; }
            const int rr0 = max(0, h0 + sh);
            const int rr1 = min(FH, h0 + eh);

            int c0[2], c1[2];
#pragma unroll
            for (int t = 0; t < 2; ++t) {
                const int j = j0 + t;
                if (j < POOL) {
                    int sw = j * wstep;
                    int ew = (j < POOL - 1) ? (j + 1) * wstep : rw;
                    if (sw == ew) { if (ew < rw) ew += 1; else sw -= 1; }
                    c0[t] = max(0, w0 + sw);
                    c1[t] = min(FW, w0 + ew);
                } else {
                    c0[t] = 0; c1[t] = 0;
                }
            }
            vf4 a0 = {-INFINITY, -INFINITY, -INFINITY, -INFINITY};
            vf4 a1 = a0;
            for (int r = rr0; r < rr1; ++r) {
                const vf4* rowp = base + (size_t)r * RS;
#pragma unroll
                for (int t = 0; t < 2; ++t) {
                    vf4 acc = (t == 0) ? a0 : a1;
                    for (int c = c0[t]; c < c1[t]; ++c) {
                        acc = vmax4(acc, rowp[c * FC4]);
                    }
                    if (t == 0) a0 = acc; else a1 = acc;
                }
            }
            __builtin_nontemporal_store(a0, o);
            if (jcnt == 2) {
                __builtin_nontemporal_store(a1, o + (size_t)FC4);
            }
        }
    }
}

extern "C" void kernel_launch(void* const* d_in, const int* in_sizes, int n_in,
                              void* d_out, int out_size, void* d_ws, size_t ws_size,
                              hipStream_t stream) {
    const float* features = (const float*)d_in[0];  // [1,50,50,1024]
    const float* rois     = (const float*)d_in[1];  // [N,4]
    float* out            = (float*)d_out;          // [N,7,7,1024]
    const int N = in_sizes[1] / 4;

    const int nunits = N * UNITS_PER_ROI;           // 8400 units per chunk
    dim3 grid(GRID);
    dim3 block(256);
    roipool_kernel<<<grid, block, 0, stream>>>(features, rois, out, nunits);
}

// Round 9
// 106.226 us; speedup vs baseline: 1.0160x; 1.0160x over previous
//
#include <hip/hip_runtime.h>
#include <math.h>

#define POOL 7
#define FH 50
#define FW 50
#define FC 1024
#define FC4 (FC / 4)        // 256 vf4 per spatial cell
#define CHUNKS 8            // 128 channels per chunk (1:1 chunk<->XCD)
#define F4C 32              // vf4 per cell per chunk = HALF a wave
#define JGROUPS 4
#define UNITS_PER_ROI (POOL * JGROUPS)   // 28
#define GRID 2048           // 8 blocks/CU; b&7 = chunk = XCD
#define NCELLS (FH * FW)    // 2500
#define QBYTES ((size_t)NCELLS * FC * sizeof(float))  // 10.24 MB

typedef float vf4 __attribute__((ext_vector_type(4)));

static __device__ __forceinline__ vf4 vmax4(vf4 a, vf4 b) {
    vf4 r;
    r.x = fmaxf(a.x, b.x);
    r.y = fmaxf(a.y, b.y);
    r.z = fmaxf(a.z, b.z);
    r.w = fmaxf(a.w, b.w);
    return r;
}

// Q[r][c] = max over fm rows {r,r+1} x cols {c,c+1} (clamped at edges).
// Same [2500][1024] layout as fm so chunk slicing is identical. Exact
// float max of the same values => bin maxes computed via overlapping Q
// lookups are bit-exact.
__global__ __launch_bounds__(256) void build_q(
    const float* __restrict__ fm, float* __restrict__ q)
{
    const int cell = blockIdx.x;
    const int t    = threadIdx.x;            // vf4 index within cell
    const int r    = cell / FW;
    const int c    = cell - r * FW;
    const int r1   = (r + 1 < FH) ? r + 1 : r;
    const int c1   = (c + 1 < FW) ? c + 1 : c;
    const vf4* f = reinterpret_cast<const vf4*>(fm);
    const vf4 v = vmax4(
        vmax4(f[(size_t)(r  * FW + c ) * FC4 + t], f[(size_t)(r1 * FW + c ) * FC4 + t]),
        vmax4(f[(size_t)(r  * FW + c1) * FC4 + t], f[(size_t)(r1 * FW + c1) * FC4 + t]));
    reinterpret_cast<vf4*>(q)[(size_t)cell * FC4 + t] = v;
}

// One bin's max into acc (per-lane, NOT yet cross-half combined).
// Half-wave pairing: lanes 0-31 (half=0) and 32-63 (half=1) read adjacent
// cells/lookups; clamped duplicates are idempotent under max.
// Q path (hr>=2 && wc>=2): row pairs qr=min(r0+2rp, r0+hr-2) and the
// paired col lookups qa=min(colb+4k+2*half, colb+wc-2) tile the bin with
// overlap — exact under max. fm path: rows x paired cols.
static __device__ __forceinline__ void do_bin(
    const vf4* __restrict__ qbase, const vf4* __restrict__ fbase, int haveQ,
    int r0, int hr, int colb, int wc, int half, vf4& acc)
{
    if (haveQ && hr >= 2 && wc >= 2) {
        const int rmax = r0 + hr - 2;
        const int cmax = colb + wc - 2;
        const int RP = (hr + 1) >> 1;
        const int KQ = (wc + 3) >> 2;
        for (int rp = 0; rp < RP; ++rp) {
            const int qr = min(r0 + 2 * rp, rmax);
            const vf4* rowp = qbase + (size_t)(qr * FW) * F4C * (FC4 / F4C); // qr*FW*FC4
            for (int k = 0; k < KQ; ++k) {
                const int qa = min(colb + 4 * k + 2 * half, cmax);
                acc = vmax4(acc, rowp[(size_t)qa * FC4]);
            }
        }
    } else {
        const int clast = colb + wc - 1;
        const int KP = (wc + 1) >> 1;
        for (int r = r0; r < r0 + hr; ++r) {
            const vf4* rowp = fbase + (size_t)(r * FW) * FC4;
            for (int k = 0; k < KP; ++k) {
                const int ca = min(colb + 2 * k + half, clast);
                acc = vmax4(acc, rowp[(size_t)ca * FC4]);
            }
        }
    }
}

static __device__ __forceinline__ vf4 cross_half_max(vf4 a) {
    vf4 o;
    o.x = __shfl_xor(a.x, 32, 64);
    o.y = __shfl_xor(a.y, 32, 64);
    o.z = __shfl_xor(a.z, 32, 64);
    o.w = __shfl_xor(a.w, 32, 64);
    return vmax4(a, o);
}

// Persistent RoI max-pool, 8-way chunked + Q-table volume cut.
//
// R8 (true 8-deep asm MLP) was null -> per-wave MLP hardware-refuted. The
// surviving model: aggregate scattered-L2 service ~9.7 TB/s; time ~ line
// volume. R7's volume test was CONFOUNDED: fm slice (2.56MB) + Q slice
// (2.56MB) = 5.1MB > 4MB per-XCD L2 -> thrash cancelled the cut. This
// version keeps footprint clean: 8 chunks of 128ch -> fm slice 1.28MB/XCD
// + Q slice 1.28MB = 2.56MB < 4MB. chunk = b&7 gives exact 1:1 chunk<->XCD
// pinning (b%8 round-robin). Half-wave pairing additionally halves VMEM
// instruction count; one shfl_xor(32) per bin merges halves.
__global__ __launch_bounds__(256, 4) void roipool_kernel(
    const float* __restrict__ fm,     // [FH, FW, FC]
    const float* __restrict__ rois,   // [N, 4] (y1, x1, y2, x2) normalized
    float* __restrict__ out,          // [N, 7, 7, FC]
    int nunits,
    const float* __restrict__ q, int haveQ)
{
    const int b     = blockIdx.x;
    const int chunk = b & (CHUNKS - 1);       // == XCD id (b%8 round-robin)
    const int wave  = threadIdx.x >> 6;
    const int lane  = threadIdx.x & 63;
    const int half  = lane >> 5;              // 0: lanes 0-31, 1: lanes 32-63
    const int sl    = lane & 31;
    const int wv    = (b >> 3) * 4 + wave;    // [0, 1024) within this chunk

    const int f4 = chunk * F4C + sl;          // vf4 within cell [0,256)
    const vf4* fbase = reinterpret_cast<const vf4*>(fm) + f4;
    const vf4* qbase = reinterpret_cast<const vf4*>(q) + f4;

    for (int u = wv; u < nunits; u += 1024) {
        const int n   = u / UNITS_PER_ROI;
        const int rem = u - n * UNITS_PER_ROI;
        const int i   = rem >> 2;
        const int jg  = rem & 3;
        const int j0  = jg * 2;
        const int jcnt = (jg < JGROUPS - 1) ? 2 : 1;

        // ROI corners: truncating float->int cast, matching jnp astype(int32)
        const float4 roi = reinterpret_cast<const float4*>(rois)[n];
        const int h0 = (int)((float)FH * roi.x);
        const int w0 = (int)((float)FW * roi.y);
        const int h1 = (int)((float)FH * roi.z);
        const int w1 = (int)((float)FW * roi.w);
        const int rh = h1 - h0;
        const int rw = w1 - w0;
        const int hstep = rh / POOL;
        const int wstep = rw / POOL;

        vf4* o = reinterpret_cast<vf4*>(out)
               + (size_t)(n * 49 + i * 7 + j0) * FC4 + f4;

        if (hstep >= 1 && wstep >= 1) {
            // ---- fast path: bins exactly partition (verified R5-R8) ----
            const int r0 = h0 + i * hstep;
            const int hr = (i < POOL - 1) ? hstep : (rh - 6 * hstep);   // >=1
            {
                const int wc   = (jg < 3) ? wstep : (rw - 6 * wstep);   // >=1
                const int colb = w0 + j0 * wstep;
                vf4 a = {-INFINITY, -INFINITY, -INFINITY, -INFINITY};
                do_bin(qbase, fbase, haveQ, r0, hr, colb, wc, half, a);
                a = cross_half_max(a);
                if (half == 0) __builtin_nontemporal_store(a, o);
            }
            if (jcnt == 2) {
                const int colb = w0 + (j0 + 1) * wstep;
                vf4 a = {-INFINITY, -INFINITY, -INFINITY, -INFINITY};
                do_bin(qbase, fbase, haveQ, r0, hr, colb, wstep, half, a);
                a = cross_half_max(a);
                if (half == 0) __builtin_nontemporal_store(a, o + (size_t)FC4);
            }
        } else {
            // ---- generic fallback (degenerate ROIs): adjusted bounds ----
            int sh = i * hstep;
            int eh = (i < POOL - 1) ? (i + 1) * hstep : rh;
            if (sh == eh) { if (eh < rh) eh += 1; else sh -= 1; }
            const int rr0 = max(0, h0 + sh);
            const int rr1 = min(FH, h0 + eh);

            for (int t = 0; t < jcnt; ++t) {
                const int j = j0 + t;
                int sw = j * wstep;
                int ew = (j < POOL - 1) ? (j + 1) * wstep : rw;
                if (sw == ew) { if (ew < rw) ew += 1; else sw -= 1; }
                const int cc0 = max(0, w0 + sw);
                const int cc1 = min(FW, w0 + ew);
                vf4 a = {-INFINITY, -INFINITY, -INFINITY, -INFINITY};
                if (cc1 > cc0 && rr1 > rr0) {
                    do_bin(qbase, fbase, 0, rr0, rr1 - rr0, cc0, cc1 - cc0,
                           half, a);
                }
                a = cross_half_max(a);
                if (half == 0) {
                    __builtin_nontemporal_store(a, o + (size_t)t * FC4);
                }
            }
        }
    }
}

extern "C" void kernel_launch(void* const* d_in, const int* in_sizes, int n_in,
                              void* d_out, int out_size, void* d_ws, size_t ws_size,
                              hipStream_t stream) {
    const float* features = (const float*)d_in[0];  // [1,50,50,1024]
    const float* rois     = (const float*)d_in[1];  // [N,4]
    float* out            = (float*)d_out;          // [N,7,7,1024]
    const int N = in_sizes[1] / 4;
    const int nunits = N * UNITS_PER_ROI;           // 8400 units per chunk

    dim3 block(256);
    int haveQ = 0;
    float* qptr = nullptr;
    if (ws_size >= QBYTES) {                        // R4 confirmed ws >= 10.24MB
        qptr = (float*)d_ws;
        haveQ = 1;
        build_q<<<dim3(NCELLS), block, 0, stream>>>(features, qptr);
    }
    roipool_kernel<<<dim3(GRID), block, 0, stream>>>(features, rois, out,
                                                     nunits, qptr, haveQ);
}